// Round 1
// baseline (541.700 us; speedup 1.0000x reference)
//
#include <hip/hip_runtime.h>

#define B_ 16
#define S_ 512
#define H_ 768
#define TS_ 20
#define IS_ 20
#define D_ 808
#define M_ 36
#define E_ 12
#define RNUM_ 97
#define D2_ 50
#define P_ (E_*E_)        // 144
#define NODES_ (M_+1)     // 37
#define NCOL_ (D2_*D_)    // 40400
#define MROWS_ (B_*E_)    // 192

// ---------------- kernel 1: mention mean-pooling (+ cls node) ----------------
// x[b, n, d]; n=0 -> cls = [enc[b,0,:768], zeros(40)]; n=1..36 -> mean over
// tokens s with mention_id[b,s]==n of concat(enc, type_emb, id_emb).
__global__ __launch_bounds__(256) void k_mention_pool(
    const float* __restrict__ enc_hid, const int* __restrict__ etype,
    const int* __restrict__ eidv, const int* __restrict__ midv,
    const float* __restrict__ type_emb, const float* __restrict__ id_emb,
    float* __restrict__ x) {
  int blk = blockIdx.x;
  int b = blk / NODES_;
  int n = blk % NODES_;
  int t = threadIdx.x;
  float* xrow = x + (size_t)(b * NODES_ + n) * D_;
  if (n == 0) {
    for (int d = t; d < D_; d += 256)
      xrow[d] = (d < H_) ? enc_hid[(size_t)(b * S_) * H_ + d] : 0.0f;
    return;
  }
  float acc[4] = {0.f, 0.f, 0.f, 0.f};
  int cnt = 0;
  for (int s = 0; s < S_; ++s) {
    int m = midv[b * S_ + s];
    if (m != n) continue;
    ++cnt;
    int ty = etype[b * S_ + s];
    int iv = eidv[b * S_ + s];
    #pragma unroll
    for (int ii = 0; ii < 4; ++ii) {
      int d = t + ii * 256;
      if (d < D_) {
        float v;
        if (d < H_) v = enc_hid[(size_t)(b * S_ + s) * H_ + d];
        else if (d < H_ + TS_) v = type_emb[ty * TS_ + (d - H_)];
        else v = id_emb[iv * IS_ + (d - H_ - TS_)];
        acc[ii] += v;
      }
    }
  }
  float inv = (cnt > 0) ? 1.0f / (float)cnt : 0.0f;
  #pragma unroll
  for (int ii = 0; ii < 4; ++ii) {
    int d = t + ii * 256;
    if (d < D_) xrow[d] = acc[ii] * inv;
  }
}

// ---------------- kernel 2: entity mean-pooling over mentions ----------------
// ent[b, e, d] = (1/sum_m tbl[b,e+1,m]) * sum_m tbl[b,e+1,m] * x[b,m,d]
__global__ __launch_bounds__(256) void k_entity_pool(
    const float* __restrict__ x, const float* __restrict__ tbl,
    float* __restrict__ ent) {
  int blk = blockIdx.x;
  int b = blk / E_;
  int e = blk % E_;
  int t = threadIdx.x;
  const float* trow = tbl + (size_t)(b * (E_ + 1) + (e + 1)) * NODES_;
  __shared__ float w[NODES_];
  __shared__ float sinv;
  if (t < NODES_) w[t] = trow[t];
  __syncthreads();
  if (t == 0) {
    float s = 0.f;
    for (int m = 0; m < NODES_; ++m) s += w[m];
    sinv = (s > 0.f) ? 1.0f / s : 0.0f;
  }
  __syncthreads();
  float inv = sinv;
  for (int d = t; d < D_; d += 256) {
    float a = 0.f;
    for (int m = 0; m < NODES_; ++m)
      a += w[m] * x[(size_t)(b * NODES_ + m) * D_ + d];
    ent[(size_t)(b * E_ + e) * D_ + d] = a * inv;
  }
}

// ---------------- kernel 3: A[192,40400] = Ent[192,808] @ Wview[808,40400] ---
// fp32 baseline GEMM, BM=BN=64, BK=16, 4x4 per thread.
__global__ __launch_bounds__(256) void k_gemm(
    const float* __restrict__ Ent, const float* __restrict__ Wf,
    float* __restrict__ A) {
  __shared__ float As[16][64];   // [k][m]
  __shared__ float Bs[16][64];   // [k][n]
  const int tid = threadIdx.x;
  const int tx = tid & 15;
  const int ty = tid >> 4;
  const int rowBase = blockIdx.y * 64;   // 0,64,128 (192 rows exactly)
  const int colBase = blockIdx.x * 64;
  float acc[4][4] = {};
  for (int k0 = 0; k0 < D_; k0 += 16) {
    {   // stage A tile (64 rows x 16 k), transposed into As[k][m]
      int m = tid >> 2;
      int k4 = (tid & 3) * 4;
      const float* src = Ent + (size_t)(rowBase + m) * D_ + k0 + k4;
      #pragma unroll
      for (int i = 0; i < 4; ++i)
        As[k4 + i][m] = (k0 + k4 + i < D_) ? src[i] : 0.0f;
    }
    {   // stage B tile (16 k x 64 cols)
      int k = tid >> 4;
      int c4 = (tid & 15) * 4;
      int col = colBase + c4;
      const float* src = Wf + (size_t)(k0 + k) * NCOL_ + col;
      #pragma unroll
      for (int i = 0; i < 4; ++i)
        Bs[k][c4 + i] = (k0 + k < D_ && col + i < NCOL_) ? src[i] : 0.0f;
    }
    __syncthreads();
    #pragma unroll
    for (int kk = 0; kk < 16; ++kk) {
      float4 av = *(const float4*)&As[kk][ty * 4];
      float4 bv = *(const float4*)&Bs[kk][tx * 4];
      float a[4] = {av.x, av.y, av.z, av.w};
      float bb[4] = {bv.x, bv.y, bv.z, bv.w};
      #pragma unroll
      for (int i = 0; i < 4; ++i)
        #pragma unroll
        for (int j = 0; j < 4; ++j)
          acc[i][j] += a[i] * bb[j];
    }
    __syncthreads();
  }
  #pragma unroll
  for (int i = 0; i < 4; ++i) {
    int row = rowBase + ty * 4 + i;
    #pragma unroll
    for (int j = 0; j < 4; ++j) {
      int col = colBase + tx * 4 + j;
      if (col < NCOL_) A[(size_t)row * NCOL_ + col] = acc[i][j];
    }
  }
}

// ---------------- kernel 4: tail contraction + BN + R projection ------------
// block = (b, ke). z[je,r] = dot(A[(b,ke), r*808: ], ent[b,je,:]); BN;
// out[b, ke*12+je, k] = sum_r z[je,r] * R[k,r].
__global__ __launch_bounds__(256) void k_score(
    const float* __restrict__ A, const float* __restrict__ ent,
    const float* __restrict__ Rm, const float* __restrict__ gam,
    const float* __restrict__ bet, const float* __restrict__ mu,
    const float* __restrict__ var, float* __restrict__ out) {
  int blk = blockIdx.x;         // b*12 + ke
  int b = blk / E_;
  int ke = blk % E_;
  int t = threadIdx.x;
  int lane = t & 63;
  int wv = t >> 6;
  __shared__ float entS[E_][D_];   // 38784 B
  __shared__ float stripe[D_];     // 3232 B
  __shared__ float zS[E_ * D2_];   // 2400 B
  for (int i = t; i < E_ * D_; i += 256)
    entS[i / D_][i % D_] = ent[(size_t)(b * E_) * D_ + i];
  __syncthreads();
  const float* arow = A + (size_t)blk * NCOL_;
  for (int r = 0; r < D2_; ++r) {
    for (int j = t; j < D_; j += 256) stripe[j] = arow[r * D_ + j];
    __syncthreads();
    #pragma unroll
    for (int round = 0; round < 3; ++round) {
      int je = wv + round * 4;
      float p = 0.f;
      for (int j = lane; j < D_; j += 64) p += stripe[j] * entS[je][j];
      #pragma unroll
      for (int off = 32; off > 0; off >>= 1) p += __shfl_down(p, off, 64);
      if (lane == 0) zS[je * D2_ + r] = p;
    }
    __syncthreads();
  }
  for (int i = t; i < E_ * D2_; i += 256) {
    int r = i % D2_;
    zS[i] = (zS[i] - mu[r]) * rsqrtf(var[r] + 1e-5f) * gam[r] + bet[r];
  }
  __syncthreads();
  for (int o = t; o < E_ * RNUM_; o += 256) {
    int je = o / RNUM_;
    int k = o % RNUM_;
    float s = 0.f;
    #pragma unroll
    for (int r = 0; r < D2_; ++r) s += zS[je * D2_ + r] * Rm[k * D2_ + r];
    out[(size_t)b * (P_ * RNUM_) + (size_t)(ke * E_ + je) * RNUM_ + k] = s;
  }
}

extern "C" void kernel_launch(void* const* d_in, const int* in_sizes, int n_in,
                              void* d_out, int out_size, void* d_ws, size_t ws_size,
                              hipStream_t stream) {
  const float* enc  = (const float*)d_in[0];
  const int*  etype = (const int*)d_in[1];
  const int*  eidv  = (const int*)d_in[2];
  const int*  midv  = (const int*)d_in[3];
  const float* tbl  = (const float*)d_in[4];
  const float* temb = (const float*)d_in[5];
  const float* iemb = (const float*)d_in[6];
  const float* W    = (const float*)d_in[7];
  const float* Rm   = (const float*)d_in[8];
  const float* gam  = (const float*)d_in[9];
  const float* bet  = (const float*)d_in[10];
  const float* mu   = (const float*)d_in[11];
  const float* var  = (const float*)d_in[12];

  float* ws  = (float*)d_ws;
  float* x   = ws;                       // 16*37*808   = 478336 floats
  float* ent = x + (size_t)B_ * NODES_ * D_;      // 192*808 = 155136 floats
  float* A   = ent + (size_t)MROWS_ * D_;         // 192*40400 = 7756800 floats
  float* out = (float*)d_out;

  hipLaunchKernelGGL(k_mention_pool, dim3(B_ * NODES_), dim3(256), 0, stream,
                     enc, etype, eidv, midv, temb, iemb, x);
  hipLaunchKernelGGL(k_entity_pool, dim3(MROWS_), dim3(256), 0, stream,
                     x, tbl, ent);
  hipLaunchKernelGGL(k_gemm, dim3((NCOL_ + 63) / 64, 3), dim3(256), 0, stream,
                     ent, W, A);
  hipLaunchKernelGGL(k_score, dim3(MROWS_), dim3(256), 0, stream,
                     A, ent, Rm, gam, bet, mu, var, out);
}

// Round 2
// 210.192 us; speedup vs baseline: 2.5772x; 2.5772x over previous
//
#include <hip/hip_runtime.h>

#define B_ 16
#define S_ 512
#define H_ 768
#define TS_ 20
#define IS_ 20
#define D_ 808
#define M_ 36
#define E_ 12
#define RNUM_ 97
#define D2_ 50
#define P_ (E_*E_)        // 144
#define NODES_ (M_+1)     // 37
#define NCOL_ (D2_*D_)    // 40400
#define MROWS_ (B_*E_)    // 192
#define KPAD_ 832         // 26*32

typedef __attribute__((ext_vector_type(8))) short bf16x8;
typedef __attribute__((ext_vector_type(4))) short short4v;
typedef __attribute__((ext_vector_type(4))) float f32x4;

__device__ inline unsigned short f2bf(float f) {
  union { float f; unsigned u; } v; v.f = f;
  unsigned r = v.u + 0x7FFFu + ((v.u >> 16) & 1u);
  return (unsigned short)(r >> 16);
}

// ---------------- kernel 1: mention mean-pooling (+ cls node) ----------------
__global__ __launch_bounds__(256) void k_mention_pool(
    const float* __restrict__ enc_hid, const int* __restrict__ etype,
    const int* __restrict__ eidv, const int* __restrict__ midv,
    const float* __restrict__ type_emb, const float* __restrict__ id_emb,
    float* __restrict__ x) {
  int blk = blockIdx.x;
  int b = blk / NODES_;
  int n = blk % NODES_;
  int t = threadIdx.x;
  float* xrow = x + (size_t)(b * NODES_ + n) * D_;
  if (n == 0) {
    for (int d = t; d < D_; d += 256)
      xrow[d] = (d < H_) ? enc_hid[(size_t)(b * S_) * H_ + d] : 0.0f;
    return;
  }
  float acc[4] = {0.f, 0.f, 0.f, 0.f};
  int cnt = 0;
  for (int s = 0; s < S_; ++s) {
    int m = midv[b * S_ + s];
    if (m != n) continue;
    ++cnt;
    int ty = etype[b * S_ + s];
    int iv = eidv[b * S_ + s];
    #pragma unroll
    for (int ii = 0; ii < 4; ++ii) {
      int d = t + ii * 256;
      if (d < D_) {
        float v;
        if (d < H_) v = enc_hid[(size_t)(b * S_ + s) * H_ + d];
        else if (d < H_ + TS_) v = type_emb[ty * TS_ + (d - H_)];
        else v = id_emb[iv * IS_ + (d - H_ - TS_)];
        acc[ii] += v;
      }
    }
  }
  float inv = (cnt > 0) ? 1.0f / (float)cnt : 0.0f;
  #pragma unroll
  for (int ii = 0; ii < 4; ++ii) {
    int d = t + ii * 256;
    if (d < D_) xrow[d] = acc[ii] * inv;
  }
}

// ---------------- kernel 2: entity mean-pooling over mentions ----------------
__global__ __launch_bounds__(256) void k_entity_pool(
    const float* __restrict__ x, const float* __restrict__ tbl,
    float* __restrict__ ent) {
  int blk = blockIdx.x;
  int b = blk / E_;
  int e = blk % E_;
  int t = threadIdx.x;
  const float* trow = tbl + (size_t)(b * (E_ + 1) + (e + 1)) * NODES_;
  __shared__ float w[NODES_];
  __shared__ float sinv;
  if (t < NODES_) w[t] = trow[t];
  __syncthreads();
  if (t == 0) {
    float s = 0.f;
    for (int m = 0; m < NODES_; ++m) s += w[m];
    sinv = (s > 0.f) ? 1.0f / s : 0.0f;
  }
  __syncthreads();
  float inv = sinv;
  for (int d = t; d < D_; d += 256) {
    float a = 0.f;
    for (int m = 0; m < NODES_; ++m)
      a += w[m] * x[(size_t)(b * NODES_ + m) * D_ + d];
    ent[(size_t)(b * E_ + e) * D_ + d] = a * inv;
  }
}

// ---------------- kernel 3: A[192,40400] = Ent[192,808] @ Wview[808,40400] ---
// bf16 MFMA GEMM; both operands converted fp32->bf16 in-kernel during staging.
// BM=64 BN=128 BK=32; 4 waves, each 32x64 (2x4 tiles of 16x16), acc fp32.
__global__ __launch_bounds__(256) void k_gemm(
    const float* __restrict__ Ent, const float* __restrict__ Wf,
    float* __restrict__ A) {
  __shared__ short As[64][40];       // [m][k], pad 32->40 (80B rows)
  __shared__ short Bs[4][128][8];    // [kgroup][col][k-in-group]
  const int tid = threadIdx.x;
  const int lane = tid & 63;
  const int ln15 = lane & 15;
  const int g = lane >> 4;           // k-group 0..3
  const int g8 = g * 8;
  const int wv = tid >> 6;
  const int wr = wv >> 1;            // wave row 0..1 (32 rows each)
  const int wc = wv & 1;             // wave col 0..1 (64 cols each)
  const int rowBase = blockIdx.y * 64;
  const int colBase = blockIdx.x * 128;

  // B staging assignment: one column per thread, 16 k's
  const int colL = tid & 127;
  const int khalf = (tid >> 7) * 16;
  const int colG = colBase + colL;
  const bool cok = colG < NCOL_;

  f32x4 acc[2][4];
  #pragma unroll
  for (int i = 0; i < 2; ++i)
    #pragma unroll
    for (int j = 0; j < 4; ++j)
      acc[i][j] = (f32x4){0.f, 0.f, 0.f, 0.f};

  for (int k0 = 0; k0 < KPAD_; k0 += 32) {
    // ---- stage A tile: 64 rows x 32 k, fp32 -> bf16
    #pragma unroll
    for (int rep = 0; rep < 2; ++rep) {
      int idx = tid + rep * 256;
      int row = idx >> 3;
      int k4 = (idx & 7) * 4;
      int k = k0 + k4;
      float4 v;
      if (k < D_) v = *(const float4*)&Ent[(size_t)(rowBase + row) * D_ + k];
      else { v.x = v.y = v.z = v.w = 0.f; }
      short4v s;
      s[0] = (short)f2bf(v.x); s[1] = (short)f2bf(v.y);
      s[2] = (short)f2bf(v.z); s[3] = (short)f2bf(v.w);
      *(short4v*)&As[row][k4] = s;
    }
    // ---- stage B tile: 32 k x 128 cols, column-per-thread scalar loads
    {
      float vals[16];
      #pragma unroll
      for (int kk = 0; kk < 16; ++kk) {
        int k = k0 + khalf + kk;
        vals[kk] = (cok && k < D_) ? Wf[(size_t)k * NCOL_ + colG] : 0.f;
      }
      bf16x8 lo, hi;
      #pragma unroll
      for (int i = 0; i < 8; ++i) {
        lo[i] = (short)f2bf(vals[i]);
        hi[i] = (short)f2bf(vals[8 + i]);
      }
      int g0 = khalf >> 3;  // 0 or 2
      *(bf16x8*)&Bs[g0][colL][0] = lo;
      *(bf16x8*)&Bs[g0 + 1][colL][0] = hi;
    }
    __syncthreads();
    // ---- MFMA: 2 m-tiles x 4 n-tiles
    bf16x8 af[2], bfr[4];
    #pragma unroll
    for (int mt = 0; mt < 2; ++mt)
      af[mt] = *(const bf16x8*)&As[wr * 32 + mt * 16 + ln15][g8];
    #pragma unroll
    for (int nt = 0; nt < 4; ++nt)
      bfr[nt] = *(const bf16x8*)&Bs[g][wc * 64 + nt * 16 + ln15][0];
    #pragma unroll
    for (int mt = 0; mt < 2; ++mt)
      #pragma unroll
      for (int nt = 0; nt < 4; ++nt)
        acc[mt][nt] = __builtin_amdgcn_mfma_f32_16x16x32_bf16(
            af[mt], bfr[nt], acc[mt][nt], 0, 0, 0);
    __syncthreads();
  }

  // ---- epilogue: C/D layout col=lane&15, row=(lane>>4)*4+j
  #pragma unroll
  for (int mt = 0; mt < 2; ++mt) {
    #pragma unroll
    for (int nt = 0; nt < 4; ++nt) {
      int col = colBase + wc * 64 + nt * 16 + ln15;
      if (col < NCOL_) {
        int row = rowBase + wr * 32 + mt * 16 + g * 4;
        #pragma unroll
        for (int j = 0; j < 4; ++j)
          A[(size_t)(row + j) * NCOL_ + col] = acc[mt][nt][j];
      }
    }
  }
}

// ---------------- kernel 4: tail contraction + BN + R projection ------------
// block = (b, ke). Wave-parallel over r (no syncthreads in main loop).
__global__ __launch_bounds__(256) void k_score(
    const float* __restrict__ A, const float* __restrict__ ent,
    const float* __restrict__ Rm, const float* __restrict__ gam,
    const float* __restrict__ bet, const float* __restrict__ mu,
    const float* __restrict__ var, float* __restrict__ out) {
  int blk = blockIdx.x;         // b*12 + ke
  int b = blk / E_;
  int t = threadIdx.x;
  int lane = t & 63;
  int wv = t >> 6;
  __shared__ float entS[E_][D_];     // 38784 B
  __shared__ float zS[D2_ * E_];     // [r][je], 2400 B
  {
    const float4* src = (const float4*)(ent + (size_t)(b * E_) * D_);
    float4* dst = (float4*)&entS[0][0];
    for (int i = t; i < E_ * D_ / 4; i += 256) dst[i] = src[i];
  }
  __syncthreads();
  const float* arow = A + (size_t)blk * NCOL_;
  for (int r = wv; r < D2_; r += 4) {
    float p[E_];
    #pragma unroll
    for (int je = 0; je < E_; ++je) p[je] = 0.f;
    for (int j = lane; j < D_; j += 64) {
      float a = arow[r * D_ + j];
      #pragma unroll
      for (int je = 0; je < E_; ++je) p[je] += a * entS[je][j];
    }
    #pragma unroll
    for (int je = 0; je < E_; ++je)
      #pragma unroll
      for (int off = 32; off > 0; off >>= 1)
        p[je] += __shfl_down(p[je], off, 64);
    if (lane == 0) {
      #pragma unroll
      for (int je = 0; je < E_; ++je) zS[r * E_ + je] = p[je];
    }
  }
  __syncthreads();
  for (int i = t; i < D2_ * E_; i += 256) {
    int r = i / E_;
    zS[i] = (zS[i] - mu[r]) * rsqrtf(var[r] + 1e-5f) * gam[r] + bet[r];
  }
  __syncthreads();
  for (int o = t; o < E_ * RNUM_; o += 256) {
    int je = o / RNUM_;
    int kk = o % RNUM_;
    float s = 0.f;
    #pragma unroll
    for (int r = 0; r < D2_; ++r) s += zS[r * E_ + je] * Rm[kk * D2_ + r];
    out[(size_t)blk * (E_ * RNUM_) + o] = s;
  }
}

extern "C" void kernel_launch(void* const* d_in, const int* in_sizes, int n_in,
                              void* d_out, int out_size, void* d_ws, size_t ws_size,
                              hipStream_t stream) {
  const float* enc  = (const float*)d_in[0];
  const int*  etype = (const int*)d_in[1];
  const int*  eidv  = (const int*)d_in[2];
  const int*  midv  = (const int*)d_in[3];
  const float* tbl  = (const float*)d_in[4];
  const float* temb = (const float*)d_in[5];
  const float* iemb = (const float*)d_in[6];
  const float* W    = (const float*)d_in[7];
  const float* Rm   = (const float*)d_in[8];
  const float* gam  = (const float*)d_in[9];
  const float* bet  = (const float*)d_in[10];
  const float* mu   = (const float*)d_in[11];
  const float* var  = (const float*)d_in[12];

  float* ws  = (float*)d_ws;
  float* x   = ws;                                // 16*37*808   = 478336 floats
  float* ent = x + (size_t)B_ * NODES_ * D_;      // 192*808     = 155136 floats
  float* A   = ent + (size_t)MROWS_ * D_;         // 192*40400   = 7756800 floats
  float* out = (float*)d_out;

  hipLaunchKernelGGL(k_mention_pool, dim3(B_ * NODES_), dim3(256), 0, stream,
                     enc, etype, eidv, midv, temb, iemb, x);
  hipLaunchKernelGGL(k_entity_pool, dim3(MROWS_), dim3(256), 0, stream,
                     x, tbl, ent);
  hipLaunchKernelGGL(k_gemm, dim3((NCOL_ + 127) / 128, 3), dim3(256), 0, stream,
                     ent, W, A);
  hipLaunchKernelGGL(k_score, dim3(MROWS_), dim3(256), 0, stream,
                     A, ent, Rm, gam, bet, mu, var, out);
}

// Round 3
// 150.732 us; speedup vs baseline: 3.5938x; 1.3945x over previous
//
#include <hip/hip_runtime.h>
#include <hip/hip_bf16.h>

#define B_ 16
#define S_ 512
#define H_ 768
#define TS_ 20
#define IS_ 20
#define D_ 808
#define M_ 36
#define E_ 12
#define RNUM_ 97
#define D2_ 50
#define P_ (E_*E_)        // 144
#define NODES_ (M_+1)     // 37
#define NCOL_ (D2_*D_)    // 40400
#define MROWS_ (B_*E_)    // 192
#define KSTEPS_ 26
#define KPAD_ (KSTEPS_*32)  // 832

typedef __attribute__((ext_vector_type(8))) short bf16x8;
typedef __attribute__((ext_vector_type(4))) float f32x4;

__device__ inline unsigned short f2bf(float f) {
  union { float f; unsigned u; } v; v.f = f;
  unsigned r = v.u + 0x7FFFu + ((v.u >> 16) & 1u);
  return (unsigned short)(r >> 16);
}

__device__ inline void gll16(const float* src, void* lds) {
  __builtin_amdgcn_global_load_lds(
      (const __attribute__((address_space(1))) unsigned int*)src,
      (__attribute__((address_space(3))) unsigned int*)lds, 16, 0, 0);
}

// ---------------- kernel 1: mention mean-pooling (+ cls node) ----------------
__global__ __launch_bounds__(256) void k_mention_pool(
    const float* __restrict__ enc_hid, const int* __restrict__ etype,
    const int* __restrict__ eidv, const int* __restrict__ midv,
    const float* __restrict__ type_emb, const float* __restrict__ id_emb,
    float* __restrict__ x) {
  int blk = blockIdx.x;
  int b = blk / NODES_;
  int n = blk % NODES_;
  int t = threadIdx.x;
  float* xrow = x + (size_t)(b * NODES_ + n) * D_;
  if (n == 0) {
    for (int d = t; d < D_; d += 256)
      xrow[d] = (d < H_) ? enc_hid[(size_t)(b * S_) * H_ + d] : 0.0f;
    return;
  }
  float acc[4] = {0.f, 0.f, 0.f, 0.f};
  int cnt = 0;
  for (int s = 0; s < S_; ++s) {
    int m = midv[b * S_ + s];
    if (m != n) continue;
    ++cnt;
    int ty = etype[b * S_ + s];
    int iv = eidv[b * S_ + s];
    #pragma unroll
    for (int ii = 0; ii < 4; ++ii) {
      int d = t + ii * 256;
      if (d < D_) {
        float v;
        if (d < H_) v = enc_hid[(size_t)(b * S_ + s) * H_ + d];
        else if (d < H_ + TS_) v = type_emb[ty * TS_ + (d - H_)];
        else v = id_emb[iv * IS_ + (d - H_ - TS_)];
        acc[ii] += v;
      }
    }
  }
  float inv = (cnt > 0) ? 1.0f / (float)cnt : 0.0f;
  #pragma unroll
  for (int ii = 0; ii < 4; ++ii) {
    int d = t + ii * 256;
    if (d < D_) xrow[d] = acc[ii] * inv;
  }
}

// ---------------- kernel 2: entity pooling + bf16 pre-swizzled A -------------
// ent fp32 [192][808]; eswz bf16 layout [kb=26][g=4][row=192][8] zero-padded.
__global__ __launch_bounds__(256) void k_entity_pool(
    const float* __restrict__ x, const float* __restrict__ tbl,
    float* __restrict__ ent, short* __restrict__ eswz) {
  int blk = blockIdx.x;
  int b = blk / E_;
  int e = blk % E_;
  int t = threadIdx.x;
  const float* trow = tbl + (size_t)(b * (E_ + 1) + (e + 1)) * NODES_;
  __shared__ float w[NODES_];
  __shared__ float sinv;
  if (t < NODES_) w[t] = trow[t];
  __syncthreads();
  if (t == 0) {
    float s = 0.f;
    for (int m = 0; m < NODES_; ++m) s += w[m];
    sinv = (s > 0.f) ? 1.0f / s : 0.0f;
  }
  __syncthreads();
  float inv = sinv;
  for (int d = t; d < D_; d += 256) {
    float a = 0.f;
    for (int m = 0; m < NODES_; ++m)
      a += w[m] * x[(size_t)(b * NODES_ + m) * D_ + d];
    float v = a * inv;
    ent[(size_t)blk * D_ + d] = v;
    int kb = d >> 5, g = (d >> 3) & 3, el = d & 7;
    eswz[((size_t)(kb * 4 + g) * MROWS_ + blk) * 8 + el] = (short)f2bf(v);
  }
  if (t < KPAD_ - D_) {   // zero-pad k = 808..831
    int d = D_ + t;
    int kb = d >> 5, g = (d >> 3) & 3, el = d & 7;
    eswz[((size_t)(kb * 4 + g) * MROWS_ + blk) * 8 + el] = 0;
  }
}

// ---------------- kernel 3: A[192,40400] = Ent @ Wview -----------------------
// BM=192 BN=64 BK=32. W fp32 -> LDS via global_load_lds (dbuf), cvt at read.
// A-frags: direct coalesced bf16 loads from pre-swizzled eswz (L2-hot).
__global__ __launch_bounds__(256) void k_gemm(
    const float* __restrict__ Wf, const short* __restrict__ eswz,
    float* __restrict__ A) {
  __shared__ float Bs[2][32][64];   // 16 KiB
  const int tid = threadIdx.x;
  const int lane = tid & 63;
  const int ln15 = lane & 15;
  const int g = lane >> 4;
  const int wv = tid >> 6;
  const int colBase = blockIdx.x * 64;

  // staging coords: flat = r2*256 + tid -> k = flat>>4, col4 = (flat&15)*4
  const int sk = tid >> 4;
  const int sc = (tid & 15) * 4;
  const int scol = (colBase + sc + 3 < NCOL_) ? (colBase + sc) : (NCOL_ - 4);

  f32x4 acc[3][4];
  #pragma unroll
  for (int i = 0; i < 3; ++i)
    #pragma unroll
    for (int j = 0; j < 4; ++j)
      acc[i][j] = (f32x4){0.f, 0.f, 0.f, 0.f};

  // prologue stage tile 0 into buf 0
  #pragma unroll
  for (int r2 = 0; r2 < 2; ++r2) {
    int kg = r2 * 16 + sk;          // t = 0
    if (kg > D_ - 1) kg = D_ - 1;
    gll16(Wf + (size_t)kg * NCOL_ + scol,
          (char*)&Bs[0][0][0] + (size_t)(r2 * 1024 + wv * 256) * 4);
  }
  __syncthreads();

  int buf = 0;
  for (int t = 0; t < KSTEPS_; ++t) {
    if (t + 1 < KSTEPS_) {
      #pragma unroll
      for (int r2 = 0; r2 < 2; ++r2) {
        int kg = (t + 1) * 32 + r2 * 16 + sk;
        if (kg > D_ - 1) kg = D_ - 1;
        gll16(Wf + (size_t)kg * NCOL_ + scol,
              (char*)&Bs[buf ^ 1][0][0] + (size_t)(r2 * 1024 + wv * 256) * 4);
      }
    }
    // A fragments: direct global bf16 (pre-swizzled, L2-resident)
    bf16x8 af[3];
    const short* ab = eswz + ((size_t)(t * 4 + g) * MROWS_ + wv * 48 + ln15) * 8;
    af[0] = *(const bf16x8*)(ab);
    af[1] = *(const bf16x8*)(ab + 16 * 8);
    af[2] = *(const bf16x8*)(ab + 32 * 8);
    // B fragments: fp32 LDS (transposed scalar reads) -> packed bf16
    bf16x8 bfr[4];
    #pragma unroll
    for (int nt = 0; nt < 4; ++nt) {
      float f[8];
      #pragma unroll
      for (int e = 0; e < 8; ++e) f[e] = Bs[buf][g * 8 + e][nt * 16 + ln15];
      union { bf16x8 v; __hip_bfloat162 h[4]; } u;
      #pragma unroll
      for (int e2 = 0; e2 < 4; ++e2)
        u.h[e2] = __float22bfloat162_rn(make_float2(f[2 * e2], f[2 * e2 + 1]));
      bfr[nt] = u.v;
    }
    #pragma unroll
    for (int mt = 0; mt < 3; ++mt)
      #pragma unroll
      for (int nt = 0; nt < 4; ++nt)
        acc[mt][nt] = __builtin_amdgcn_mfma_f32_16x16x32_bf16(
            af[mt], bfr[nt], acc[mt][nt], 0, 0, 0);
    __syncthreads();
    buf ^= 1;
  }

  // epilogue: C/D layout col = lane&15, row = g*4 + j
  #pragma unroll
  for (int mt = 0; mt < 3; ++mt) {
    int row = wv * 48 + mt * 16 + g * 4;
    #pragma unroll
    for (int nt = 0; nt < 4; ++nt) {
      int col = colBase + nt * 16 + ln15;
      if (col < NCOL_) {
        #pragma unroll
        for (int j = 0; j < 4; ++j)
          A[(size_t)(row + j) * NCOL_ + col] = acc[mt][nt][j];
      }
    }
  }
}

// ---------------- kernel 4a: z[blk][r][je] = dot(A-row-slice, ent) ----------
// grid (192, 13): one r per wave, 2496 blocks.
__global__ __launch_bounds__(256) void k_score_z(
    const float* __restrict__ A, const float* __restrict__ ent,
    float* __restrict__ zbuf) {
  int blk = blockIdx.x;         // b*12 + ke
  int rc = blockIdx.y;          // 0..12
  int b = blk / E_;
  int t = threadIdx.x;
  int lane = t & 63;
  int wv = t >> 6;
  __shared__ float entS[E_ * D_];   // 38784 B
  {
    const float4* src = (const float4*)(ent + (size_t)b * E_ * D_);
    float4* dst = (float4*)entS;
    for (int i = t; i < E_ * D_ / 4; i += 256) dst[i] = src[i];
  }
  __syncthreads();
  int r = rc * 4 + wv;
  if (r >= D2_) return;
  const float* arow = A + (size_t)blk * NCOL_ + (size_t)r * D_;
  float p[E_];
  #pragma unroll
  for (int je = 0; je < E_; ++je) p[je] = 0.f;
  for (int j = lane; j < D_; j += 64) {
    float a = arow[j];
    #pragma unroll
    for (int je = 0; je < E_; ++je) p[je] += a * entS[je * D_ + j];
  }
  #pragma unroll
  for (int je = 0; je < E_; ++je)
    #pragma unroll
    for (int off = 32; off > 0; off >>= 1)
      p[je] += __shfl_down(p[je], off, 64);
  if (lane == 0) {
    #pragma unroll
    for (int je = 0; je < E_; ++je)
      zbuf[(size_t)blk * (D2_ * E_) + r * E_ + je] = p[je];
  }
}

// ---------------- kernel 4b: BN + R projection ------------------------------
__global__ __launch_bounds__(256) void k_out(
    const float* __restrict__ zbuf, const float* __restrict__ Rm,
    const float* __restrict__ gam, const float* __restrict__ bet,
    const float* __restrict__ mu, const float* __restrict__ var,
    float* __restrict__ out) {
  int blk = blockIdx.x;   // b*12+ke
  int t = threadIdx.x;
  __shared__ float zS[D2_ * E_];       // 600
  __shared__ float Rs[RNUM_ * D2_];    // 4850
  for (int i = t; i < D2_ * E_; i += 256) {
    int r = i / E_;
    float z = zbuf[(size_t)blk * (D2_ * E_) + i];
    zS[i] = (z - mu[r]) * rsqrtf(var[r] + 1e-5f) * gam[r] + bet[r];
  }
  for (int i = t; i < RNUM_ * D2_; i += 256) Rs[i] = Rm[i];
  __syncthreads();
  for (int o = t; o < E_ * RNUM_; o += 256) {
    int je = o / RNUM_;
    int k = o % RNUM_;
    float s = 0.f;
    #pragma unroll
    for (int r = 0; r < D2_; ++r) s += zS[r * E_ + je] * Rs[k * D2_ + r];
    out[(size_t)blk * (E_ * RNUM_) + o] = s;
  }
}

extern "C" void kernel_launch(void* const* d_in, const int* in_sizes, int n_in,
                              void* d_out, int out_size, void* d_ws, size_t ws_size,
                              hipStream_t stream) {
  const float* enc  = (const float*)d_in[0];
  const int*  etype = (const int*)d_in[1];
  const int*  eidv  = (const int*)d_in[2];
  const int*  midv  = (const int*)d_in[3];
  const float* tbl  = (const float*)d_in[4];
  const float* temb = (const float*)d_in[5];
  const float* iemb = (const float*)d_in[6];
  const float* W    = (const float*)d_in[7];
  const float* Rm   = (const float*)d_in[8];
  const float* gam  = (const float*)d_in[9];
  const float* bet  = (const float*)d_in[10];
  const float* mu   = (const float*)d_in[11];
  const float* var  = (const float*)d_in[12];

  float* ws   = (float*)d_ws;
  float* x    = ws;                                  // 478336 floats
  float* ent  = x + (size_t)B_ * NODES_ * D_;        // +155136 -> 633472
  float* A    = ent + (size_t)MROWS_ * D_;           // +7756800 -> 8390272
  float* zbuf = A + (size_t)MROWS_ * NCOL_;          // +115200 -> 8505472
  short* eswz = (short*)(zbuf + (size_t)MROWS_ * D2_ * E_);  // 319488 B
  float* out  = (float*)d_out;

  hipLaunchKernelGGL(k_mention_pool, dim3(B_ * NODES_), dim3(256), 0, stream,
                     enc, etype, eidv, midv, temb, iemb, x);
  hipLaunchKernelGGL(k_entity_pool, dim3(MROWS_), dim3(256), 0, stream,
                     x, tbl, ent, eswz);
  hipLaunchKernelGGL(k_gemm, dim3((NCOL_ + 63) / 64), dim3(256), 0, stream,
                     W, eswz, A);
  hipLaunchKernelGGL(k_score_z, dim3(MROWS_, 13), dim3(256), 0, stream,
                     A, ent, zbuf);
  hipLaunchKernelGGL(k_out, dim3(MROWS_), dim3(256), 0, stream,
                     zbuf, Rm, gam, bet, mu, var, out);
}